// Round 15
// baseline (874.750 us; speedup 1.0000x reference)
//
#include <hip/hip_runtime.h>
#include <math.h>

// Problem constants
#define B_   64
#define C_   256
#define L_   1600          // H*W = 40*40
#define T_   25            // tokens per window (5x5)
#define ROWS (B_*L_)       // 102400
#define QSCALE 0.17677669529663687f   // 1/sqrt(32)

typedef _Float16 f16;
typedef f16 f16x8 __attribute__((ext_vector_type(8)));
typedef f16 f16x4 __attribute__((ext_vector_type(4)));
typedef f16 f16x2 __attribute__((ext_vector_type(2)));
typedef float f32x4 __attribute__((ext_vector_type(4)));

__device__ __forceinline__ void gload_lds16(const void* g, void* l) {
  __builtin_amdgcn_global_load_lds(
      (const __attribute__((address_space(1))) unsigned int*)g,
      (__attribute__((address_space(3))) unsigned int*)l, 16, 0, 0);
}

__device__ __forceinline__ float dot8(f16x8 a, f16x8 b, float acc) {
  union U { f16x8 v; f16x2 p[4]; };
  U ua; ua.v = a;
  U ub; ub.v = b;
#pragma unroll
  for (int i = 0; i < 4; ++i)
    acc = __builtin_amdgcn_fdot2(ua.p[i], ub.p[i], acc, false);
  return acc;
}

// ---------------------------------------------------------------------------
// Weight convert+transpose (tiled, coalesced): o(N,K) f16 = w(K,N)^T
__global__ __launch_bounds__(256) void wtrans(const float* __restrict__ w,
                                              f16* __restrict__ o, int K, int N) {
  __shared__ f16 tile[64][72];
  int tid = threadIdx.x;
  int n0 = blockIdx.x * 64, k0 = blockIdx.y * 64;
  int nn = tid & 63, kq = tid >> 6;
#pragma unroll
  for (int i = 0; i < 16; ++i) {
    int k = kq * 16 + i;
    tile[nn][k] = (f16)w[(size_t)(k0 + k) * N + n0 + nn];
  }
  __syncthreads();
#pragma unroll
  for (int jj = 0; jj < 2; ++jj) {
    int e = jj * 256 + tid;
    int nr = e >> 3, kb = e & 7;
    *(f16x8*)&o[(size_t)(n0 + nr) * K + k0 + kb * 8] = *(const f16x8*)&tile[nr][kb * 8];
  }
}

// ---------------------------------------------------------------------------
// LN1 fused (stats + apply + transpose): xs(ROWS,256) f16 from x(B,C,L)
__global__ __launch_bounds__(256) void ln1_fused(const float* __restrict__ x,
    const float* __restrict__ g, const float* __restrict__ be,
    f16* __restrict__ xs) {
  __shared__ float t32[256][65];
  __shared__ float gL[256], beL[256];
  int tid = threadIdx.x;
  gL[tid] = g[tid]; beL[tid] = be[tid];
  int r0 = blockIdx.x * 64;
  int w = tid >> 6, rl = tid & 63;
  int grow = r0 + rl;
  int b = grow / L_, l = grow - b * L_;
  const float* xb = x + (size_t)b * (C_ * L_) + l;
#pragma unroll
  for (int i = 0; i < 64; ++i) {
    int c = w + i * 4;
    t32[c][rl] = xb[(size_t)c * L_];
  }
  __syncthreads();
  int row = tid >> 2, q = tid & 3;
  float s = 0.f, s2 = 0.f;
#pragma unroll
  for (int i = 0; i < 64; ++i) {
    float vv = t32[q * 64 + i][row];
    s += vv; s2 += vv * vv;
  }
  s += __shfl_xor(s, 1); s2 += __shfl_xor(s2, 1);
  s += __shfl_xor(s, 2); s2 += __shfl_xor(s2, 2);
  float m = s * (1.0f / 256.0f);
  float rr = rsqrtf(s2 * (1.0f / 256.0f) - m * m + 1e-5f);
  f16* orow = &xs[(size_t)(r0 + row) * 256 + q * 64];
#pragma unroll
  for (int z8 = 0; z8 < 8; ++z8) {
    f16x8 ov;
#pragma unroll
    for (int z = 0; z < 8; ++z) {
      int c = q * 64 + z8 * 8 + z;
      ov[z] = (f16)((t32[c][row] - m) * rr * gL[c] + beL[c]);
    }
    *(f16x8*)(orow + z8 * 8) = ov;
  }
}

// ---------------------------------------------------------------------------
// MFMA GEMM v8: block tile 128x256, 256 threads = 4 waves (2M x 2N), wave
// tile 64x128 (acc 4x8 f32x4). Same proven 3-RING + COUNTED-vmcnt schedule,
// staging geometry (64-row groups) and XOR swizzle as v5 -- ONLY the tile
// shape changed: LDS reads drop 0.5 -> 0.375 b128/MFMA and MFMA-per-barrier
// doubles (128/block-K-step). 6 loads/thread/tile -> steady wait vmcnt(6).
// LDS 72 KB -> 2 blocks/CU. XCD-affinity grid swizzle. setprio (T5).
// EPI: 0 = +bias -> f16 ; 2 = tanh-gelu(+bias) -> f16
//      3 = +bias +resid(f16) -> transposed (B,512,L) f32, direct float4 stores
template<int K, int N, int EPI, int NCB>
__global__ __launch_bounds__(256) void gemmW(
    const f16* __restrict__ A, const f16* __restrict__ BT,
    const float* __restrict__ bias,
    float* __restrict__ outF, f16* __restrict__ outH,
    const f16* __restrict__ resid, int row_off, int nrp8) {
  __shared__ f16 As[3][128 * 32];   // 8 KB per buf
  __shared__ f16 Bs[3][256 * 32];   // 16 KB per buf
  int tid = threadIdx.x;
  int w = tid >> 6, lane = tid & 63;
  int wr = w >> 1, wc = w & 1;
  int bid = blockIdx.x;
  int xcd = bid & 7, j1d = bid >> 3;
  int member = j1d % NCB, grp = j1d / NCB;
  int r0 = (xcd * nrp8 + grp) * 128;
  int n0 = member * 256;

  f32x4 acc[4][8] = {};

  int srow = tid >> 2;    // staging row within each 64-row group (0..63)
  int st4 = tid & 3;

  const int NT = K / 32;

#define STAGE_T(kt, bi)                                                       \
  {                                                                           \
    int k0s = (kt) * 32;                                                      \
    _Pragma("unroll")                                                         \
    for (int j = 0; j < 2; ++j) {                                             \
      int row = j * 64 + srow;                                                \
      int cb = st4 ^ ((row >> 1) & 3);                                        \
      gload_lds16(A + (size_t)(r0 + row) * K + k0s + cb * 8,                  \
                  &As[bi][(j * 4 + w) * 512]);                                \
    }                                                                         \
    _Pragma("unroll")                                                         \
    for (int j = 0; j < 4; ++j) {                                             \
      int row = j * 64 + srow;                                                \
      int cb = st4 ^ ((row >> 1) & 3);                                        \
      gload_lds16(BT + (size_t)(n0 + row) * K + k0s + cb * 8,                 \
                  &Bs[bi][(j * 4 + w) * 512]);                                \
    }                                                                         \
  }

#define COMPUTE_T(bi)                                                         \
  {                                                                           \
    f16x8 af[4], bf[8];                                                       \
    _Pragma("unroll")                                                         \
    for (int m = 0; m < 4; ++m) {                                             \
      int ar = wr * 64 + m * 16 + (lane & 15);                                \
      int sl = (lane >> 4) ^ ((ar >> 1) & 3);                                 \
      af[m] = *(const f16x8*)&As[bi][ar * 32 + sl * 8];                       \
    }                                                                         \
    _Pragma("unroll")                                                         \
    for (int n = 0; n < 8; ++n) {                                             \
      int br = wc * 128 + n * 16 + (lane & 15);                               \
      int sl = (lane >> 4) ^ ((br >> 1) & 3);                                 \
      bf[n] = *(const f16x8*)&Bs[bi][br * 32 + sl * 8];                       \
    }                                                                         \
    __builtin_amdgcn_s_setprio(1);                                            \
    _Pragma("unroll")                                                         \
    for (int m = 0; m < 4; ++m)                                               \
      _Pragma("unroll")                                                       \
      for (int n = 0; n < 8; ++n)                                             \
        acc[m][n] =                                                           \
            __builtin_amdgcn_mfma_f32_16x16x32_f16(af[m], bf[n], acc[m][n],   \
                                                   0, 0, 0);                  \
    __builtin_amdgcn_s_setprio(0);                                            \
  }

  // prologue: 2 tiles in flight (12 loads)
  STAGE_T(0, 0);
  STAGE_T(1, 1);

  for (int t = 0; t < NT - 1; ++t) {
    asm volatile("s_waitcnt vmcnt(6)" ::: "memory");   // tile t landed; t+1 (6 loads) in flight
    __builtin_amdgcn_s_barrier();
    COMPUTE_T(t % 3);
    if (t + 2 < NT) STAGE_T(t + 2, (t + 2) % 3);       // slot read at t-1; barrier proved reads retired
  }
  asm volatile("s_waitcnt vmcnt(0)" ::: "memory");     // peeled last tile
  __builtin_amdgcn_s_barrier();
  COMPUTE_T((NT - 1) % 3);

#undef STAGE_T
#undef COMPUTE_T

  if constexpr (EPI != 3) {
#pragma unroll
    for (int m = 0; m < 4; ++m) {
#pragma unroll
      for (int n = 0; n < 8; ++n) {
        int gcol = n0 + wc * 128 + n * 16 + (lane & 15);
        float bb = bias[gcol];
#pragma unroll
        for (int j = 0; j < 4; ++j) {
          int grow = r0 + wr * 64 + m * 16 + ((lane >> 4) << 2) + j;
          float vv = acc[m][n][j] + bb;
          if constexpr (EPI == 0) {
            outH[(size_t)grow * N + gcol] = (f16)vv;
          } else {
            // tanh-GELU (erf-GELU deviation < ~5e-4; erff was ~26% of mlp1)
            float z = 0.7978845608028654f * (vv + 0.044715f * vv * vv * vv);
            float e2 = __expf(2.0f * z);
            float th = 1.0f - 2.0f / (e2 + 1.0f);
            float gl = 0.5f * vv * (1.0f + th);
            outH[(size_t)grow * N + gcol] = (f16)gl;
          }
        }
      }
    }
  } else {
    // direct transposed store: lane holds 4 consecutive l-values of one channel
#pragma unroll
    for (int m = 0; m < 4; ++m) {
      int growl = r0 + wr * 64 + m * 16 + ((lane >> 4) << 2);
      int growg = row_off + growl;       // multiple of 4; never straddles b
      int b = growg / L_;
      int l = growg - b * L_;
#pragma unroll
      for (int n = 0; n < 8; ++n) {
        int gcol = n0 + wc * 128 + n * 16 + (lane & 15);
        float bb = bias[gcol];
        float4 o;
        o.x = acc[m][n][0] + bb + (float)resid[(size_t)(growg + 0) * 512 + gcol];
        o.y = acc[m][n][1] + bb + (float)resid[(size_t)(growg + 1) * 512 + gcol];
        o.z = acc[m][n][2] + bb + (float)resid[(size_t)(growg + 2) * 512 + gcol];
        o.w = acc[m][n][3] + bb + (float)resid[(size_t)(growg + 3) * 512 + gcol];
        *(float4*)&outF[((size_t)b * 512 + gcol) * L_ + l] = o;
      }
    }
  }
}

// ---------------------------------------------------------------------------
// Window attention v4 (unchanged from round 14): two windows per block,
// reg scores+softmax, packed-f16 PV.
#define PST 776
__global__ __launch_bounds__(512) void attn_kernel(const f16* __restrict__ qkv,
                                                   const float* __restrict__ rel,
                                                   f16* __restrict__ outp) {
  __shared__ f16 qc[2][T_][PST];  // 77600 B
  __shared__ f16 relL[81 * 8];    // 1296 B
  int tid = threadIdx.x;
  int wl = tid >> 8;              // which window (0/1)
  int tl = tid & 255;
  int bn = blockIdx.x * 2 + wl;
  int b = bn >> 6, n = bn & 63;
  int u = n >> 3, v = n & 7;

  for (int e = tid; e < 648; e += 512) relL[e] = (f16)rel[e];

  for (int e = tl; e < T_ * 96; e += 256) {
    int t = e / 96;
    int g = e - t * 96;
    int i = t / 5, j = t - i * 5;
    int l = (u * 5 + i) * 40 + v * 5 + j;
    f16x8 val = *(const f16x8*)&qkv[(size_t)(b * L_ + l) * 768 + g * 8];
    int which = g >> 5;
    int d = g & 31;
    int base = which * 256 + d;
#pragma unroll
    for (int h = 0; h < 8; ++h)
      qc[wl][t][base + h * 32] = val[h];
  }
  __syncthreads();

  int h = tl >> 5, t = tl & 31;
  if (t < T_) {
    int i1 = t / 5, j1 = t - i1 * 5;
    int par1 = (u + v + i1 + j1) & 1;
    const f16* qp = &qc[wl][t][h * 32];
    f16x8 q0 = *(const f16x8*)(qp + 0);
    f16x8 q1 = *(const f16x8*)(qp + 8);
    f16x8 q2 = *(const f16x8*)(qp + 16);
    f16x8 q3 = *(const f16x8*)(qp + 24);

    float p[T_];
    float mx = -1e30f;
#pragma unroll
    for (int s = 0; s < T_; ++s) {
      int i2 = s / 5, j2 = s - i2 * 5;
      const f16* kp = &qc[wl][s][256 + h * 32];
      f16x8 k0 = *(const f16x8*)(kp + 0);
      f16x8 k1 = *(const f16x8*)(kp + 8);
      f16x8 k2 = *(const f16x8*)(kp + 16);
      f16x8 k3 = *(const f16x8*)(kp + 24);
      float d0 = 0.f, d1 = 0.f;
      d0 = dot8(q0, k0, d0);
      d1 = dot8(q1, k1, d1);
      d0 = dot8(q2, k2, d0);
      d1 = dot8(q3, k3, d1);
      float bias = (float)relL[((i1 - i2 + 4) * 9 + (j1 - j2 + 4)) * 8 + h];
      int par2 = (u + v + i2 + j2) & 1;
      float sc = (d0 + d1) * QSCALE + bias + ((par1 & par2) ? 0.0f : -100.0f);
      p[s] = sc;
      mx = fmaxf(mx, sc);
    }
    float sum = 0.f;
#pragma unroll
    for (int s = 0; s < T_; ++s) {
      float e = __expf(p[s] - mx);
      p[s] = e;
      sum += e;
    }
    float inv = 1.0f / sum;
#pragma unroll
    for (int s = 0; s < T_; ++s) p[s] *= inv;

    int l = (u * 5 + i1) * 40 + v * 5 + j1;
    f16* op = &outp[(size_t)(b * L_ + l) * 256 + h * 32];

    f16x2 acc2[16];
#pragma unroll
    for (int k = 0; k < 16; ++k) { acc2[k][0] = (f16)0.f; acc2[k][1] = (f16)0.f; }
#pragma unroll
    for (int s = 0; s < T_; ++s) {
      const f16* vp = &qc[wl][s][512 + h * 32];
      union VU { f16x8 v8; f16x2 v2[4]; };
      VU v0, v1, v2q, v3;
      v0.v8  = *(const f16x8*)(vp + 0);
      v1.v8  = *(const f16x8*)(vp + 8);
      v2q.v8 = *(const f16x8*)(vp + 16);
      v3.v8  = *(const f16x8*)(vp + 24);
      f16 ps = (f16)p[s];
      f16x2 pp; pp[0] = ps; pp[1] = ps;
#pragma unroll
      for (int k = 0; k < 4; ++k) {
        acc2[k]      += pp * v0.v2[k];
        acc2[4 + k]  += pp * v1.v2[k];
        acc2[8 + k]  += pp * v2q.v2[k];
        acc2[12 + k] += pp * v3.v2[k];
      }
    }
#pragma unroll
    for (int z8 = 0; z8 < 4; ++z8) {
      union VU { f16x8 v8; f16x2 v2[4]; };
      VU ov;
#pragma unroll
      for (int k = 0; k < 4; ++k) ov.v2[k] = acc2[z8 * 4 + k];
      *(f16x8*)(op + z8 * 8) = ov.v8;
    }
  }
}

// ---------------------------------------------------------------------------
// LN2 fused: yln(ROWS,512) f16 = LN(y_h)*g+b
__global__ __launch_bounds__(256) void ln2_fused(const f16* __restrict__ y,
    const float* __restrict__ g, const float* __restrict__ be,
    f16* __restrict__ yln) {
  int wv = threadIdx.x >> 6, lane = threadIdx.x & 63;
  int row = blockIdx.x * 4 + wv;
  const f16x8* yp = (const f16x8*)(y + (size_t)row * 512);
  f16x8 h0 = yp[lane];
  float v[8];
  float s = 0.f, s2 = 0.f;
#pragma unroll
  for (int z = 0; z < 8; ++z) {
    v[z] = (float)h0[z];
    s += v[z]; s2 += v[z] * v[z];
  }
#pragma unroll
  for (int o = 32; o; o >>= 1) { s += __shfl_xor(s, o); s2 += __shfl_xor(s2, o); }
  float m = s * (1.0f / 512.0f);
  float rr = rsqrtf(s2 * (1.0f / 512.0f) - m * m + 1e-5f);
  float4 g0 = ((const float4*)g)[lane * 2], g1 = ((const float4*)g)[lane * 2 + 1];
  float4 b0 = ((const float4*)be)[lane * 2], b1 = ((const float4*)be)[lane * 2 + 1];
  float gg[8] = {g0.x, g0.y, g0.z, g0.w, g1.x, g1.y, g1.z, g1.w};
  float bb[8] = {b0.x, b0.y, b0.z, b0.w, b1.x, b1.y, b1.z, b1.w};
  f16x8 o8;
#pragma unroll
  for (int z = 0; z < 8; ++z)
    o8[z] = (f16)((v[z] - m) * rr * gg[z] + bb[z]);
  *(f16x8*)&yln[(size_t)row * 512 + lane * 8] = o8;
}

// ---------------------------------------------------------------------------
extern "C" void kernel_launch(void* const* d_in, const int* in_sizes, int n_in,
                              void* d_out, int out_size, void* d_ws, size_t ws_size,
                              hipStream_t stream) {
  const float* x      = (const float*)d_in[0];
  const float* qkv_w  = (const float*)d_in[1];
  const float* qkv_b  = (const float*)d_in[2];
  const float* rel    = (const float*)d_in[3];
  const float* proj_w = (const float*)d_in[4];
  const float* proj_b = (const float*)d_in[5];
  const float* w1     = (const float*)d_in[6];
  const float* b1     = (const float*)d_in[7];
  const float* w2     = (const float*)d_in[8];
  const float* b2     = (const float*)d_in[9];
  const float* g1     = (const float*)d_in[10];
  const float* be1    = (const float*)d_in[11];
  const float* g2     = (const float*)d_in[12];
  const float* be2    = (const float*)d_in[13];
  float* out = (float*)d_out;

  // ws layout (bytes): as rounds 6-14.
  char* w8 = (char*)d_ws;
  f16* qkv_wT  = (f16*)(w8 + 1638400);
  f16* proj_wT = qkv_wT + 768 * 256;
  f16* w1T     = proj_wT + 512 * 256;
  f16* w2T     = w1T + 1024 * 512;
  char* P0 = w8 + 4390912;
  f16* qkv_h = (f16*)P0;
  f16* y_h   = (f16*)P0;                      // overlays qkv_h (dead after attn)
  char* P1 = P0 + (size_t)ROWS * 768 * 2;
  f16* xs_h  = (f16*)P1;
  f16* att_h = (f16*)(P1 + (size_t)ROWS * 256 * 2);
  f16* yln   = (f16*)P1;                      // overlays xs/att (dead after proj)
  char* P2 = P1 + (size_t)ROWS * 512 * 2;
  f16* hid = (f16*)P2;

  size_t need_full = 4390912 + (size_t)ROWS * 768 * 2 + (size_t)ROWS * 512 * 2
                   + (size_t)ROWS * 1024 * 2;
  bool full = ws_size >= need_full;

  wtrans<<<dim3(768 / 64, 256 / 64), 256, 0, stream>>>(qkv_w, qkv_wT, 256, 768);
  wtrans<<<dim3(512 / 64, 256 / 64), 256, 0, stream>>>(proj_w, proj_wT, 256, 512);
  wtrans<<<dim3(1024 / 64, 512 / 64), 256, 0, stream>>>(w1, w1T, 512, 1024);
  wtrans<<<dim3(512 / 64, 1024 / 64), 256, 0, stream>>>(w2, w2T, 1024, 512);

  ln1_fused<<<ROWS / 64, 256, 0, stream>>>(x, g1, be1, xs_h);

  // 1-D swizzled grids over 128-row panels, 256-col blocks: nrp8 = (M/128)/8
  gemmW<256, 768, 0, 3><<<3 * (ROWS / 128), 256, 0, stream>>>(
      xs_h, qkv_wT, qkv_b, nullptr, qkv_h, nullptr, 0, (ROWS / 128) / 8);

  attn_kernel<<<B_ * 32, 512, 0, stream>>>(qkv_h, rel, att_h);   // 2 windows/block

  gemmW<256, 512, 0, 2><<<2 * (ROWS / 128), 256, 0, stream>>>(
      att_h, proj_wT, proj_b, nullptr, y_h, nullptr, 0, (ROWS / 128) / 8);

  ln2_fused<<<ROWS / 4, 256, 0, stream>>>(y_h, g2, be2, yln);

  if (full) {
    gemmW<512, 1024, 2, 4><<<4 * (ROWS / 128), 256, 0, stream>>>(
        yln, w1T, b1, nullptr, hid, nullptr, 0, (ROWS / 128) / 8);
    gemmW<1024, 512, 3, 2><<<2 * (ROWS / 128), 256, 0, stream>>>(
        hid, w2T, b2, out, nullptr, y_h, 0, (ROWS / 128) / 8);
  } else {
    const int CHUNK = ROWS / 4;  // 25600 rows, 200 panels -> nrp8 = 25
    for (int c = 0; c < 4; ++c) {
      int off = c * CHUNK;
      gemmW<512, 1024, 2, 4><<<4 * (CHUNK / 128), 256, 0, stream>>>(
          yln + (size_t)off * 512, w1T, b1, nullptr, hid, nullptr, off, (CHUNK / 128) / 8);
      gemmW<1024, 512, 3, 2><<<2 * (CHUNK / 128), 256, 0, stream>>>(
          hid, w2T, b2, out, nullptr, y_h, off, (CHUNK / 128) / 8);
    }
  }
  (void)in_sizes; (void)n_in; (void)out_size;
}

// Round 16
// 653.835 us; speedup vs baseline: 1.3379x; 1.3379x over previous
//
#include <hip/hip_runtime.h>
#include <math.h>

// Problem constants
#define B_   64
#define C_   256
#define L_   1600          // H*W = 40*40
#define T_   25            // tokens per window (5x5)
#define ROWS (B_*L_)       // 102400
#define QSCALE 0.17677669529663687f   // 1/sqrt(32)

typedef _Float16 f16;
typedef f16 f16x8 __attribute__((ext_vector_type(8)));
typedef f16 f16x4 __attribute__((ext_vector_type(4)));
typedef f16 f16x2 __attribute__((ext_vector_type(2)));
typedef float f32x4 __attribute__((ext_vector_type(4)));

__device__ __forceinline__ void gload_lds16(const void* g, void* l) {
  __builtin_amdgcn_global_load_lds(
      (const __attribute__((address_space(1))) unsigned int*)g,
      (__attribute__((address_space(3))) unsigned int*)l, 16, 0, 0);
}

__device__ __forceinline__ float dot8(f16x8 a, f16x8 b, float acc) {
  union U { f16x8 v; f16x2 p[4]; };
  U ua; ua.v = a;
  U ub; ub.v = b;
#pragma unroll
  for (int i = 0; i < 4; ++i)
    acc = __builtin_amdgcn_fdot2(ua.p[i], ub.p[i], acc, false);
  return acc;
}

// ---------------------------------------------------------------------------
// Fused weight convert+transpose: all four weights in ONE launch (336 blocks
// of the proven 64x64 tile body; per-block decode is wave-uniform).
__global__ __launch_bounds__(256) void wtrans_all(
    const float* __restrict__ wq, const float* __restrict__ wp,
    const float* __restrict__ wm1, const float* __restrict__ wm2,
    f16* __restrict__ oq, f16* __restrict__ op,
    f16* __restrict__ om1, f16* __restrict__ om2) {
  int bid = blockIdx.x;
  const float* w; f16* o; int K, N, nb, idx;
  if (bid < 48)       { w = wq;  o = oq;  K = 256;  N = 768;  idx = bid;       nb = 12; }
  else if (bid < 80)  { w = wp;  o = op;  K = 256;  N = 512;  idx = bid - 48;  nb = 8;  }
  else if (bid < 208) { w = wm1; o = om1; K = 512;  N = 1024; idx = bid - 80;  nb = 16; }
  else                { w = wm2; o = om2; K = 1024; N = 512;  idx = bid - 208; nb = 8;  }
  int n0 = (idx % nb) * 64, k0 = (idx / nb) * 64;

  __shared__ f16 tile[64][72];
  int tid = threadIdx.x;
  int nn = tid & 63, kq = tid >> 6;
#pragma unroll
  for (int i = 0; i < 16; ++i) {
    int k = kq * 16 + i;
    tile[nn][k] = (f16)w[(size_t)(k0 + k) * N + n0 + nn];
  }
  __syncthreads();
#pragma unroll
  for (int jj = 0; jj < 2; ++jj) {
    int e = jj * 256 + tid;
    int nr = e >> 3, kb = e & 7;
    *(f16x8*)&o[(size_t)(n0 + nr) * K + k0 + kb * 8] = *(const f16x8*)&tile[nr][kb * 8];
  }
}

// ---------------------------------------------------------------------------
// LN1 fused (stats + apply + transpose): xs(ROWS,256) f16 from x(B,C,L)
__global__ __launch_bounds__(256) void ln1_fused(const float* __restrict__ x,
    const float* __restrict__ g, const float* __restrict__ be,
    f16* __restrict__ xs) {
  __shared__ float t32[256][65];
  __shared__ float gL[256], beL[256];
  int tid = threadIdx.x;
  gL[tid] = g[tid]; beL[tid] = be[tid];
  int r0 = blockIdx.x * 64;
  int w = tid >> 6, rl = tid & 63;
  int grow = r0 + rl;
  int b = grow / L_, l = grow - b * L_;
  const float* xb = x + (size_t)b * (C_ * L_) + l;
#pragma unroll
  for (int i = 0; i < 64; ++i) {
    int c = w + i * 4;
    t32[c][rl] = xb[(size_t)c * L_];
  }
  __syncthreads();
  int row = tid >> 2, q = tid & 3;
  float s = 0.f, s2 = 0.f;
#pragma unroll
  for (int i = 0; i < 64; ++i) {
    float vv = t32[q * 64 + i][row];
    s += vv; s2 += vv * vv;
  }
  s += __shfl_xor(s, 1); s2 += __shfl_xor(s2, 1);
  s += __shfl_xor(s, 2); s2 += __shfl_xor(s2, 2);
  float m = s * (1.0f / 256.0f);
  float rr = rsqrtf(s2 * (1.0f / 256.0f) - m * m + 1e-5f);
  f16* orow = &xs[(size_t)(r0 + row) * 256 + q * 64];
#pragma unroll
  for (int z8 = 0; z8 < 8; ++z8) {
    f16x8 ov;
#pragma unroll
    for (int z = 0; z < 8; ++z) {
      int c = q * 64 + z8 * 8 + z;
      ov[z] = (f16)((t32[c][row] - m) * rr * gL[c] + beL[c]);
    }
    *(f16x8*)(orow + z8 * 8) = ov;
  }
}

// ---------------------------------------------------------------------------
// MFMA GEMM v5 (round-12 config -- measured optimum across 9 structural
// variants; rounds 13/15 confirmed wider tiles & 8-phase port both regress:
// resident-wave count dominates per-wave intensity in this latency-bound
// regime). 256 threads, 4 waves (2x2), wave tile 64x64, BK=32, 3-BUFFER RING
// + COUNTED vmcnt(4); vmcnt(0) only on peeled last tile. XCD-affinity grid
// swizzle. setprio around MFMA.
// EPI: 0 = +bias -> f16 ; 2 = tanh-gelu(+bias) -> f16
//      3 = +bias +resid(f16) -> transposed (B,512,L) f32, direct float4 stores
template<int K, int N, int EPI, int NCB>
__global__ __launch_bounds__(256) void gemm16(
    const f16* __restrict__ A, const f16* __restrict__ BT,
    const float* __restrict__ bias,
    float* __restrict__ outF, f16* __restrict__ outH,
    const f16* __restrict__ resid, int row_off, int nrp8) {
  __shared__ f16 As[3][128 * 32];
  __shared__ f16 Bs[3][128 * 32];
  int tid = threadIdx.x;
  int w = tid >> 6, lane = tid & 63;
  int wr = w >> 1, wc = w & 1;
  int bid = blockIdx.x;
  int xcd = bid & 7, j1d = bid >> 3;
  int member = j1d % NCB, grp = j1d / NCB;
  int r0 = (xcd * nrp8 + grp) * 128;
  int n0 = member * 128;

  f32x4 acc[4][4] = {};

  int srow0 = w * 16 + (lane >> 2);
  int st4 = lane & 3;

  const int NT = K / 32;

#define STAGE_T(kt, bi)                                                       \
  {                                                                           \
    int k0s = (kt) * 32;                                                      \
    _Pragma("unroll")                                                         \
    for (int i = 0; i < 2; ++i) {                                             \
      int row = i * 64 + srow0;                                               \
      int cb = st4 ^ ((row >> 1) & 3);                                        \
      gload_lds16(A + (size_t)(r0 + row) * K + k0s + cb * 8,                  \
                  &As[bi][(i * 4 + w) * 512]);                                \
    }                                                                         \
    _Pragma("unroll")                                                         \
    for (int i = 0; i < 2; ++i) {                                             \
      int row = i * 64 + srow0;                                               \
      int cb = st4 ^ ((row >> 1) & 3);                                        \
      gload_lds16(BT + (size_t)(n0 + row) * K + k0s + cb * 8,                 \
                  &Bs[bi][(i * 4 + w) * 512]);                                \
    }                                                                         \
  }

#define COMPUTE_T(bi)                                                         \
  {                                                                           \
    f16x8 af[4], bf[4];                                                       \
    _Pragma("unroll")                                                         \
    for (int m = 0; m < 4; ++m) {                                             \
      int ar = wr * 64 + m * 16 + (lane & 15);                                \
      int sl = (lane >> 4) ^ ((ar >> 1) & 3);                                 \
      af[m] = *(const f16x8*)&As[bi][ar * 32 + sl * 8];                       \
    }                                                                         \
    _Pragma("unroll")                                                         \
    for (int n = 0; n < 4; ++n) {                                             \
      int br = wc * 64 + n * 16 + (lane & 15);                                \
      int sl = (lane >> 4) ^ ((br >> 1) & 3);                                 \
      bf[n] = *(const f16x8*)&Bs[bi][br * 32 + sl * 8];                       \
    }                                                                         \
    __builtin_amdgcn_s_setprio(1);                                            \
    _Pragma("unroll")                                                         \
    for (int m = 0; m < 4; ++m)                                               \
      _Pragma("unroll")                                                       \
      for (int n = 0; n < 4; ++n)                                             \
        acc[m][n] =                                                           \
            __builtin_amdgcn_mfma_f32_16x16x32_f16(af[m], bf[n], acc[m][n],   \
                                                   0, 0, 0);                  \
    __builtin_amdgcn_s_setprio(0);                                            \
  }

  // prologue: 2 tiles in flight
  STAGE_T(0, 0);
  STAGE_T(1, 1);

  for (int t = 0; t < NT - 1; ++t) {
    asm volatile("s_waitcnt vmcnt(4)" ::: "memory");   // tile t landed; t+1 in flight
    __builtin_amdgcn_s_barrier();
    COMPUTE_T(t % 3);
    if (t + 2 < NT) STAGE_T(t + 2, (t + 2) % 3);       // slot read at t-1; barrier proves reads retired
  }
  asm volatile("s_waitcnt vmcnt(0)" ::: "memory");     // peeled last tile
  __builtin_amdgcn_s_barrier();
  COMPUTE_T((NT - 1) % 3);

#undef STAGE_T
#undef COMPUTE_T

  if constexpr (EPI != 3) {
#pragma unroll
    for (int m = 0; m < 4; ++m) {
#pragma unroll
      for (int n = 0; n < 4; ++n) {
        int gcol = n0 + wc * 64 + n * 16 + (lane & 15);
        float bb = bias[gcol];
#pragma unroll
        for (int j = 0; j < 4; ++j) {
          int grow = r0 + wr * 64 + m * 16 + ((lane >> 4) << 2) + j;
          float vv = acc[m][n][j] + bb;
          if constexpr (EPI == 0) {
            outH[(size_t)grow * N + gcol] = (f16)vv;
          } else {
            // tanh-GELU (erf-GELU deviation < ~5e-4; erff was ~26% of mlp1)
            float z = 0.7978845608028654f * (vv + 0.044715f * vv * vv * vv);
            float e2 = __expf(2.0f * z);
            float th = 1.0f - 2.0f / (e2 + 1.0f);
            float gl = 0.5f * vv * (1.0f + th);
            outH[(size_t)grow * N + gcol] = (f16)gl;
          }
        }
      }
    }
  } else {
    // direct transposed store: lane holds 4 consecutive l-values of one channel
#pragma unroll
    for (int m = 0; m < 4; ++m) {
      int growl = r0 + wr * 64 + m * 16 + ((lane >> 4) << 2);
      int growg = row_off + growl;       // multiple of 4; never straddles b
      int b = growg / L_;
      int l = growg - b * L_;
#pragma unroll
      for (int n = 0; n < 4; ++n) {
        int gcol = n0 + wc * 64 + n * 16 + (lane & 15);
        float bb = bias[gcol];
        float4 o;
        o.x = acc[m][n][0] + bb + (float)resid[(size_t)(growg + 0) * 512 + gcol];
        o.y = acc[m][n][1] + bb + (float)resid[(size_t)(growg + 1) * 512 + gcol];
        o.z = acc[m][n][2] + bb + (float)resid[(size_t)(growg + 2) * 512 + gcol];
        o.w = acc[m][n][3] + bb + (float)resid[(size_t)(growg + 3) * 512 + gcol];
        *(float4*)&outF[((size_t)b * 512 + gcol) * L_ + l] = o;
      }
    }
  }
}

// ---------------------------------------------------------------------------
// Window attention v4 (round-14): two windows per block (512 threads,
// 78.9 KB LDS -> 2 blocks/CU), reg scores+softmax, packed-f16 PV.
#define PST 776
__global__ __launch_bounds__(512) void attn_kernel(const f16* __restrict__ qkv,
                                                   const float* __restrict__ rel,
                                                   f16* __restrict__ outp) {
  __shared__ f16 qc[2][T_][PST];  // 77600 B
  __shared__ f16 relL[81 * 8];    // 1296 B
  int tid = threadIdx.x;
  int wl = tid >> 8;              // which window (0/1)
  int tl = tid & 255;
  int bn = blockIdx.x * 2 + wl;
  int b = bn >> 6, n = bn & 63;
  int u = n >> 3, v = n & 7;

  for (int e = tid; e < 648; e += 512) relL[e] = (f16)rel[e];

  for (int e = tl; e < T_ * 96; e += 256) {
    int t = e / 96;
    int g = e - t * 96;
    int i = t / 5, j = t - i * 5;
    int l = (u * 5 + i) * 40 + v * 5 + j;
    f16x8 val = *(const f16x8*)&qkv[(size_t)(b * L_ + l) * 768 + g * 8];
    int which = g >> 5;
    int d = g & 31;
    int base = which * 256 + d;
#pragma unroll
    for (int h = 0; h < 8; ++h)
      qc[wl][t][base + h * 32] = val[h];
  }
  __syncthreads();

  int h = tl >> 5, t = tl & 31;
  if (t < T_) {
    int i1 = t / 5, j1 = t - i1 * 5;
    int par1 = (u + v + i1 + j1) & 1;
    const f16* qp = &qc[wl][t][h * 32];
    f16x8 q0 = *(const f16x8*)(qp + 0);
    f16x8 q1 = *(const f16x8*)(qp + 8);
    f16x8 q2 = *(const f16x8*)(qp + 16);
    f16x8 q3 = *(const f16x8*)(qp + 24);

    float p[T_];
    float mx = -1e30f;
#pragma unroll
    for (int s = 0; s < T_; ++s) {
      int i2 = s / 5, j2 = s - i2 * 5;
      const f16* kp = &qc[wl][s][256 + h * 32];
      f16x8 k0 = *(const f16x8*)(kp + 0);
      f16x8 k1 = *(const f16x8*)(kp + 8);
      f16x8 k2 = *(const f16x8*)(kp + 16);
      f16x8 k3 = *(const f16x8*)(kp + 24);
      float d0 = 0.f, d1 = 0.f;
      d0 = dot8(q0, k0, d0);
      d1 = dot8(q1, k1, d1);
      d0 = dot8(q2, k2, d0);
      d1 = dot8(q3, k3, d1);
      float bias = (float)relL[((i1 - i2 + 4) * 9 + (j1 - j2 + 4)) * 8 + h];
      int par2 = (u + v + i2 + j2) & 1;
      float sc = (d0 + d1) * QSCALE + bias + ((par1 & par2) ? 0.0f : -100.0f);
      p[s] = sc;
      mx = fmaxf(mx, sc);
    }
    float sum = 0.f;
#pragma unroll
    for (int s = 0; s < T_; ++s) {
      float e = __expf(p[s] - mx);
      p[s] = e;
      sum += e;
    }
    float inv = 1.0f / sum;
#pragma unroll
    for (int s = 0; s < T_; ++s) p[s] *= inv;

    int l = (u * 5 + i1) * 40 + v * 5 + j1;
    f16* op = &outp[(size_t)(b * L_ + l) * 256 + h * 32];

    f16x2 acc2[16];
#pragma unroll
    for (int k = 0; k < 16; ++k) { acc2[k][0] = (f16)0.f; acc2[k][1] = (f16)0.f; }
#pragma unroll
    for (int s = 0; s < T_; ++s) {
      const f16* vp = &qc[wl][s][512 + h * 32];
      union VU { f16x8 v8; f16x2 v2[4]; };
      VU v0, v1, v2q, v3;
      v0.v8  = *(const f16x8*)(vp + 0);
      v1.v8  = *(const f16x8*)(vp + 8);
      v2q.v8 = *(const f16x8*)(vp + 16);
      v3.v8  = *(const f16x8*)(vp + 24);
      f16 ps = (f16)p[s];
      f16x2 pp; pp[0] = ps; pp[1] = ps;
#pragma unroll
      for (int k = 0; k < 4; ++k) {
        acc2[k]      += pp * v0.v2[k];
        acc2[4 + k]  += pp * v1.v2[k];
        acc2[8 + k]  += pp * v2q.v2[k];
        acc2[12 + k] += pp * v3.v2[k];
      }
    }
#pragma unroll
    for (int z8 = 0; z8 < 4; ++z8) {
      union VU { f16x8 v8; f16x2 v2[4]; };
      VU ov;
#pragma unroll
      for (int k = 0; k < 4; ++k) ov.v2[k] = acc2[z8 * 4 + k];
      *(f16x8*)(op + z8 * 8) = ov.v8;
    }
  }
}

// ---------------------------------------------------------------------------
// LN2 fused: yln(ROWS,512) f16 = LN(y_h)*g+b
__global__ __launch_bounds__(256) void ln2_fused(const f16* __restrict__ y,
    const float* __restrict__ g, const float* __restrict__ be,
    f16* __restrict__ yln) {
  int wv = threadIdx.x >> 6, lane = threadIdx.x & 63;
  int row = blockIdx.x * 4 + wv;
  const f16x8* yp = (const f16x8*)(y + (size_t)row * 512);
  f16x8 h0 = yp[lane];
  float v[8];
  float s = 0.f, s2 = 0.f;
#pragma unroll
  for (int z = 0; z < 8; ++z) {
    v[z] = (float)h0[z];
    s += v[z]; s2 += v[z] * v[z];
  }
#pragma unroll
  for (int o = 32; o; o >>= 1) { s += __shfl_xor(s, o); s2 += __shfl_xor(s2, o); }
  float m = s * (1.0f / 512.0f);
  float rr = rsqrtf(s2 * (1.0f / 512.0f) - m * m + 1e-5f);
  float4 g0 = ((const float4*)g)[lane * 2], g1 = ((const float4*)g)[lane * 2 + 1];
  float4 b0 = ((const float4*)be)[lane * 2], b1 = ((const float4*)be)[lane * 2 + 1];
  float gg[8] = {g0.x, g0.y, g0.z, g0.w, g1.x, g1.y, g1.z, g1.w};
  float bb[8] = {b0.x, b0.y, b0.z, b0.w, b1.x, b1.y, b1.z, b1.w};
  f16x8 o8;
#pragma unroll
  for (int z = 0; z < 8; ++z)
    o8[z] = (f16)((v[z] - m) * rr * gg[z] + bb[z]);
  *(f16x8*)&yln[(size_t)row * 512 + lane * 8] = o8;
}

// ---------------------------------------------------------------------------
extern "C" void kernel_launch(void* const* d_in, const int* in_sizes, int n_in,
                              void* d_out, int out_size, void* d_ws, size_t ws_size,
                              hipStream_t stream) {
  const float* x      = (const float*)d_in[0];
  const float* qkv_w  = (const float*)d_in[1];
  const float* qkv_b  = (const float*)d_in[2];
  const float* rel    = (const float*)d_in[3];
  const float* proj_w = (const float*)d_in[4];
  const float* proj_b = (const float*)d_in[5];
  const float* w1     = (const float*)d_in[6];
  const float* b1     = (const float*)d_in[7];
  const float* w2     = (const float*)d_in[8];
  const float* b2     = (const float*)d_in[9];
  const float* g1     = (const float*)d_in[10];
  const float* be1    = (const float*)d_in[11];
  const float* g2     = (const float*)d_in[12];
  const float* be2    = (const float*)d_in[13];
  float* out = (float*)d_out;

  // ws layout (bytes): as rounds 6-14.
  char* w8 = (char*)d_ws;
  f16* qkv_wT  = (f16*)(w8 + 1638400);
  f16* proj_wT = qkv_wT + 768 * 256;
  f16* w1T     = proj_wT + 512 * 256;
  f16* w2T     = w1T + 1024 * 512;
  char* P0 = w8 + 4390912;
  f16* qkv_h = (f16*)P0;
  f16* y_h   = (f16*)P0;                      // overlays qkv_h (dead after attn)
  char* P1 = P0 + (size_t)ROWS * 768 * 2;
  f16* xs_h  = (f16*)P1;
  f16* att_h = (f16*)(P1 + (size_t)ROWS * 256 * 2);
  f16* yln   = (f16*)P1;                      // overlays xs/att (dead after proj)
  char* P2 = P1 + (size_t)ROWS * 512 * 2;
  f16* hid = (f16*)P2;

  size_t need_full = 4390912 + (size_t)ROWS * 768 * 2 + (size_t)ROWS * 512 * 2
                   + (size_t)ROWS * 1024 * 2;
  bool full = ws_size >= need_full;

  wtrans_all<<<336, 256, 0, stream>>>(qkv_w, proj_w, w1, w2,
                                      qkv_wT, proj_wT, w1T, w2T);

  ln1_fused<<<ROWS / 64, 256, 0, stream>>>(x, g1, be1, xs_h);

  // 1-D swizzled grids: nrp8 = (M/128)/8
  gemm16<256, 768, 0, 6><<<6 * (ROWS / 128), 256, 0, stream>>>(
      xs_h, qkv_wT, qkv_b, nullptr, qkv_h, nullptr, 0, (ROWS / 128) / 8);

  attn_kernel<<<B_ * 32, 512, 0, stream>>>(qkv_h, rel, att_h);   // 2 windows/block

  gemm16<256, 512, 0, 4><<<4 * (ROWS / 128), 256, 0, stream>>>(
      att_h, proj_wT, proj_b, nullptr, y_h, nullptr, 0, (ROWS / 128) / 8);

  ln2_fused<<<ROWS / 4, 256, 0, stream>>>(y_h, g2, be2, yln);

  if (full) {
    gemm16<512, 1024, 2, 8><<<8 * (ROWS / 128), 256, 0, stream>>>(
        yln, w1T, b1, nullptr, hid, nullptr, 0, (ROWS / 128) / 8);
    gemm16<1024, 512, 3, 4><<<4 * (ROWS / 128), 256, 0, stream>>>(
        hid, w2T, b2, out, nullptr, y_h, 0, (ROWS / 128) / 8);
  } else {
    const int CHUNK = ROWS / 4;  // 25600 rows, 200 panels -> nrp8 = 25
    for (int c = 0; c < 4; ++c) {
      int off = c * CHUNK;
      gemm16<512, 1024, 2, 8><<<8 * (CHUNK / 128), 256, 0, stream>>>(
          yln + (size_t)off * 512, w1T, b1, nullptr, hid, nullptr, off, (CHUNK / 128) / 8);
      gemm16<1024, 512, 3, 4><<<4 * (CHUNK / 128), 256, 0, stream>>>(
          hid, w2T, b2, out, nullptr, y_h, off, (CHUNK / 128) / 8);
    }
  }
  (void)in_sizes; (void)n_in; (void)out_size;
}

// Round 17
// 652.356 us; speedup vs baseline: 1.3409x; 1.0023x over previous
//
#include <hip/hip_runtime.h>
#include <math.h>

// Problem constants
#define B_   64
#define C_   256
#define L_   1600          // H*W = 40*40
#define T_   25            // tokens per window (5x5)
#define ROWS (B_*L_)       // 102400
#define QSCALE 0.17677669529663687f   // 1/sqrt(32)

typedef _Float16 f16;
typedef f16 f16x8 __attribute__((ext_vector_type(8)));
typedef f16 f16x4 __attribute__((ext_vector_type(4)));
typedef f16 f16x2 __attribute__((ext_vector_type(2)));
typedef float f32x4 __attribute__((ext_vector_type(4)));

__device__ __forceinline__ void gload_lds16(const void* g, void* l) {
  __builtin_amdgcn_global_load_lds(
      (const __attribute__((address_space(1))) unsigned int*)g,
      (__attribute__((address_space(3))) unsigned int*)l, 16, 0, 0);
}

__device__ __forceinline__ float dot8(f16x8 a, f16x8 b, float acc) {
  union U { f16x8 v; f16x2 p[4]; };
  U ua; ua.v = a;
  U ub; ub.v = b;
#pragma unroll
  for (int i = 0; i < 4; ++i)
    acc = __builtin_amdgcn_fdot2(ua.p[i], ub.p[i], acc, false);
  return acc;
}

// ---------------------------------------------------------------------------
// Fused weight convert+transpose: all four weights in ONE launch (336 blocks
// of the proven 64x64 tile body; per-block decode is wave-uniform).
__global__ __launch_bounds__(256) void wtrans_all(
    const float* __restrict__ wq, const float* __restrict__ wp,
    const float* __restrict__ wm1, const float* __restrict__ wm2,
    f16* __restrict__ oq, f16* __restrict__ op,
    f16* __restrict__ om1, f16* __restrict__ om2) {
  int bid = blockIdx.x;
  const float* w; f16* o; int K, N, nb, idx;
  if (bid < 48)       { w = wq;  o = oq;  K = 256;  N = 768;  idx = bid;       nb = 12; }
  else if (bid < 80)  { w = wp;  o = op;  K = 256;  N = 512;  idx = bid - 48;  nb = 8;  }
  else if (bid < 208) { w = wm1; o = om1; K = 512;  N = 1024; idx = bid - 80;  nb = 16; }
  else                { w = wm2; o = om2; K = 1024; N = 512;  idx = bid - 208; nb = 8;  }
  int n0 = (idx % nb) * 64, k0 = (idx / nb) * 64;

  __shared__ f16 tile[64][72];
  int tid = threadIdx.x;
  int nn = tid & 63, kq = tid >> 6;
#pragma unroll
  for (int i = 0; i < 16; ++i) {
    int k = kq * 16 + i;
    tile[nn][k] = (f16)w[(size_t)(k0 + k) * N + n0 + nn];
  }
  __syncthreads();
#pragma unroll
  for (int jj = 0; jj < 2; ++jj) {
    int e = jj * 256 + tid;
    int nr = e >> 3, kb = e & 7;
    *(f16x8*)&o[(size_t)(n0 + nr) * K + k0 + kb * 8] = *(const f16x8*)&tile[nr][kb * 8];
  }
}

// ---------------------------------------------------------------------------
// LN1 fused (stats + apply + transpose): xs(ROWS,256) f16 from x(B,C,L).
// Round-17 fix: per-q STAGGERED read order. Old pattern t32[q*64+i][row] had
// bank = (i+row)%32 independent of q -> the 4 q-lanes sharing a row always
// collided (4-way on all 128 reads; SQ_LDS_BANK_CONFLICT = 7.07e6 measured).
// ii=(i+8q)&63 / z8'=(z8+2q)&7 make bank = (i+8q+row)%32: each residue hit
// exactly 2x -> 2-way = free (m136). Sums are order-invariant; output
// granules are per-thread so write order is irrelevant.
__global__ __launch_bounds__(256) void ln1_fused(const float* __restrict__ x,
    const float* __restrict__ g, const float* __restrict__ be,
    f16* __restrict__ xs) {
  __shared__ float t32[256][65];
  __shared__ float gL[256], beL[256];
  int tid = threadIdx.x;
  gL[tid] = g[tid]; beL[tid] = be[tid];
  int r0 = blockIdx.x * 64;
  int w = tid >> 6, rl = tid & 63;
  int grow = r0 + rl;
  int b = grow / L_, l = grow - b * L_;
  const float* xb = x + (size_t)b * (C_ * L_) + l;
#pragma unroll
  for (int i = 0; i < 64; ++i) {
    int c = w + i * 4;
    t32[c][rl] = xb[(size_t)c * L_];
  }
  __syncthreads();
  int row = tid >> 2, q = tid & 3;
  float s = 0.f, s2 = 0.f;
#pragma unroll
  for (int i = 0; i < 64; ++i) {
    int ii = (i + q * 8) & 63;                 // bank stagger (2-way, free)
    float vv = t32[q * 64 + ii][row];
    s += vv; s2 += vv * vv;
  }
  s += __shfl_xor(s, 1); s2 += __shfl_xor(s2, 1);
  s += __shfl_xor(s, 2); s2 += __shfl_xor(s2, 2);
  float m = s * (1.0f / 256.0f);
  float rr = rsqrtf(s2 * (1.0f / 256.0f) - m * m + 1e-5f);
  f16* orow = &xs[(size_t)(r0 + row) * 256 + q * 64];
#pragma unroll
  for (int z8 = 0; z8 < 8; ++z8) {
    int zb = (z8 + q * 2) & 7;                 // bank stagger (2-way, free)
    f16x8 ov;
#pragma unroll
    for (int z = 0; z < 8; ++z) {
      int c = q * 64 + zb * 8 + z;
      ov[z] = (f16)((t32[c][row] - m) * rr * gL[c] + beL[c]);
    }
    *(f16x8*)(orow + zb * 8) = ov;
  }
}

// ---------------------------------------------------------------------------
// MFMA GEMM v5 (round-12 config -- measured optimum across 9 structural
// variants; rounds 13/15 confirmed wider tiles & 8-phase port both regress:
// resident-wave count dominates per-wave intensity in this latency-bound
// regime). 256 threads, 4 waves (2x2), wave tile 64x64, BK=32, 3-BUFFER RING
// + COUNTED vmcnt(4); vmcnt(0) only on peeled last tile. XCD-affinity grid
// swizzle. setprio around MFMA.
// EPI: 0 = +bias -> f16 ; 2 = tanh-gelu(+bias) -> f16
//      3 = +bias +resid(f16) -> transposed (B,512,L) f32, direct float4 stores
template<int K, int N, int EPI, int NCB>
__global__ __launch_bounds__(256) void gemm16(
    const f16* __restrict__ A, const f16* __restrict__ BT,
    const float* __restrict__ bias,
    float* __restrict__ outF, f16* __restrict__ outH,
    const f16* __restrict__ resid, int row_off, int nrp8) {
  __shared__ f16 As[3][128 * 32];
  __shared__ f16 Bs[3][128 * 32];
  int tid = threadIdx.x;
  int w = tid >> 6, lane = tid & 63;
  int wr = w >> 1, wc = w & 1;
  int bid = blockIdx.x;
  int xcd = bid & 7, j1d = bid >> 3;
  int member = j1d % NCB, grp = j1d / NCB;
  int r0 = (xcd * nrp8 + grp) * 128;
  int n0 = member * 128;

  f32x4 acc[4][4] = {};

  int srow0 = w * 16 + (lane >> 2);
  int st4 = lane & 3;

  const int NT = K / 32;

#define STAGE_T(kt, bi)                                                       \
  {                                                                           \
    int k0s = (kt) * 32;                                                      \
    _Pragma("unroll")                                                         \
    for (int i = 0; i < 2; ++i) {                                             \
      int row = i * 64 + srow0;                                               \
      int cb = st4 ^ ((row >> 1) & 3);                                        \
      gload_lds16(A + (size_t)(r0 + row) * K + k0s + cb * 8,                  \
                  &As[bi][(i * 4 + w) * 512]);                                \
    }                                                                         \
    _Pragma("unroll")                                                         \
    for (int i = 0; i < 2; ++i) {                                             \
      int row = i * 64 + srow0;                                               \
      int cb = st4 ^ ((row >> 1) & 3);                                        \
      gload_lds16(BT + (size_t)(n0 + row) * K + k0s + cb * 8,                 \
                  &Bs[bi][(i * 4 + w) * 512]);                                \
    }                                                                         \
  }

#define COMPUTE_T(bi)                                                         \
  {                                                                           \
    f16x8 af[4], bf[4];                                                       \
    _Pragma("unroll")                                                         \
    for (int m = 0; m < 4; ++m) {                                             \
      int ar = wr * 64 + m * 16 + (lane & 15);                                \
      int sl = (lane >> 4) ^ ((ar >> 1) & 3);                                 \
      af[m] = *(const f16x8*)&As[bi][ar * 32 + sl * 8];                       \
    }                                                                         \
    _Pragma("unroll")                                                         \
    for (int n = 0; n < 4; ++n) {                                             \
      int br = wc * 64 + n * 16 + (lane & 15);                                \
      int sl = (lane >> 4) ^ ((br >> 1) & 3);                                 \
      bf[n] = *(const f16x8*)&Bs[bi][br * 32 + sl * 8];                       \
    }                                                                         \
    __builtin_amdgcn_s_setprio(1);                                            \
    _Pragma("unroll")                                                         \
    for (int m = 0; m < 4; ++m)                                               \
      _Pragma("unroll")                                                       \
      for (int n = 0; n < 4; ++n)                                             \
        acc[m][n] =                                                           \
            __builtin_amdgcn_mfma_f32_16x16x32_f16(af[m], bf[n], acc[m][n],   \
                                                   0, 0, 0);                  \
    __builtin_amdgcn_s_setprio(0);                                            \
  }

  // prologue: 2 tiles in flight
  STAGE_T(0, 0);
  STAGE_T(1, 1);

  for (int t = 0; t < NT - 1; ++t) {
    asm volatile("s_waitcnt vmcnt(4)" ::: "memory");   // tile t landed; t+1 in flight
    __builtin_amdgcn_s_barrier();
    COMPUTE_T(t % 3);
    if (t + 2 < NT) STAGE_T(t + 2, (t + 2) % 3);       // slot read at t-1; barrier proves reads retired
  }
  asm volatile("s_waitcnt vmcnt(0)" ::: "memory");     // peeled last tile
  __builtin_amdgcn_s_barrier();
  COMPUTE_T((NT - 1) % 3);

#undef STAGE_T
#undef COMPUTE_T

  if constexpr (EPI != 3) {
#pragma unroll
    for (int m = 0; m < 4; ++m) {
#pragma unroll
      for (int n = 0; n < 4; ++n) {
        int gcol = n0 + wc * 64 + n * 16 + (lane & 15);
        float bb = bias[gcol];
#pragma unroll
        for (int j = 0; j < 4; ++j) {
          int grow = r0 + wr * 64 + m * 16 + ((lane >> 4) << 2) + j;
          float vv = acc[m][n][j] + bb;
          if constexpr (EPI == 0) {
            outH[(size_t)grow * N + gcol] = (f16)vv;
          } else {
            // tanh-GELU (erf-GELU deviation < ~5e-4; erff was ~26% of mlp1)
            float z = 0.7978845608028654f * (vv + 0.044715f * vv * vv * vv);
            float e2 = __expf(2.0f * z);
            float th = 1.0f - 2.0f / (e2 + 1.0f);
            float gl = 0.5f * vv * (1.0f + th);
            outH[(size_t)grow * N + gcol] = (f16)gl;
          }
        }
      }
    }
  } else {
    // direct transposed store: lane holds 4 consecutive l-values of one channel
#pragma unroll
    for (int m = 0; m < 4; ++m) {
      int growl = r0 + wr * 64 + m * 16 + ((lane >> 4) << 2);
      int growg = row_off + growl;       // multiple of 4; never straddles b
      int b = growg / L_;
      int l = growg - b * L_;
#pragma unroll
      for (int n = 0; n < 4; ++n) {
        int gcol = n0 + wc * 64 + n * 16 + (lane & 15);
        float bb = bias[gcol];
        float4 o;
        o.x = acc[m][n][0] + bb + (float)resid[(size_t)(growg + 0) * 512 + gcol];
        o.y = acc[m][n][1] + bb + (float)resid[(size_t)(growg + 1) * 512 + gcol];
        o.z = acc[m][n][2] + bb + (float)resid[(size_t)(growg + 2) * 512 + gcol];
        o.w = acc[m][n][3] + bb + (float)resid[(size_t)(growg + 3) * 512 + gcol];
        *(float4*)&outF[((size_t)b * 512 + gcol) * L_ + l] = o;
      }
    }
  }
}

// ---------------------------------------------------------------------------
// Window attention v4 (round-14): two windows per block (512 threads,
// 78.9 KB LDS -> 2 blocks/CU), reg scores+softmax, packed-f16 PV.
#define PST 776
__global__ __launch_bounds__(512) void attn_kernel(const f16* __restrict__ qkv,
                                                   const float* __restrict__ rel,
                                                   f16* __restrict__ outp) {
  __shared__ f16 qc[2][T_][PST];  // 77600 B
  __shared__ f16 relL[81 * 8];    // 1296 B
  int tid = threadIdx.x;
  int wl = tid >> 8;              // which window (0/1)
  int tl = tid & 255;
  int bn = blockIdx.x * 2 + wl;
  int b = bn >> 6, n = bn & 63;
  int u = n >> 3, v = n & 7;

  for (int e = tid; e < 648; e += 512) relL[e] = (f16)rel[e];

  for (int e = tl; e < T_ * 96; e += 256) {
    int t = e / 96;
    int g = e - t * 96;
    int i = t / 5, j = t - i * 5;
    int l = (u * 5 + i) * 40 + v * 5 + j;
    f16x8 val = *(const f16x8*)&qkv[(size_t)(b * L_ + l) * 768 + g * 8];
    int which = g >> 5;
    int d = g & 31;
    int base = which * 256 + d;
#pragma unroll
    for (int h = 0; h < 8; ++h)
      qc[wl][t][base + h * 32] = val[h];
  }
  __syncthreads();

  int h = tl >> 5, t = tl & 31;
  if (t < T_) {
    int i1 = t / 5, j1 = t - i1 * 5;
    int par1 = (u + v + i1 + j1) & 1;
    const f16* qp = &qc[wl][t][h * 32];
    f16x8 q0 = *(const f16x8*)(qp + 0);
    f16x8 q1 = *(const f16x8*)(qp + 8);
    f16x8 q2 = *(const f16x8*)(qp + 16);
    f16x8 q3 = *(const f16x8*)(qp + 24);

    float p[T_];
    float mx = -1e30f;
#pragma unroll
    for (int s = 0; s < T_; ++s) {
      int i2 = s / 5, j2 = s - i2 * 5;
      const f16* kp = &qc[wl][s][256 + h * 32];
      f16x8 k0 = *(const f16x8*)(kp + 0);
      f16x8 k1 = *(const f16x8*)(kp + 8);
      f16x8 k2 = *(const f16x8*)(kp + 16);
      f16x8 k3 = *(const f16x8*)(kp + 24);
      float d0 = 0.f, d1 = 0.f;
      d0 = dot8(q0, k0, d0);
      d1 = dot8(q1, k1, d1);
      d0 = dot8(q2, k2, d0);
      d1 = dot8(q3, k3, d1);
      float bias = (float)relL[((i1 - i2 + 4) * 9 + (j1 - j2 + 4)) * 8 + h];
      int par2 = (u + v + i2 + j2) & 1;
      float sc = (d0 + d1) * QSCALE + bias + ((par1 & par2) ? 0.0f : -100.0f);
      p[s] = sc;
      mx = fmaxf(mx, sc);
    }
    float sum = 0.f;
#pragma unroll
    for (int s = 0; s < T_; ++s) {
      float e = __expf(p[s] - mx);
      p[s] = e;
      sum += e;
    }
    float inv = 1.0f / sum;
#pragma unroll
    for (int s = 0; s < T_; ++s) p[s] *= inv;

    int l = (u * 5 + i1) * 40 + v * 5 + j1;
    f16* op = &outp[(size_t)(b * L_ + l) * 256 + h * 32];

    f16x2 acc2[16];
#pragma unroll
    for (int k = 0; k < 16; ++k) { acc2[k][0] = (f16)0.f; acc2[k][1] = (f16)0.f; }
#pragma unroll
    for (int s = 0; s < T_; ++s) {
      const f16* vp = &qc[wl][s][512 + h * 32];
      union VU { f16x8 v8; f16x2 v2[4]; };
      VU v0, v1, v2q, v3;
      v0.v8  = *(const f16x8*)(vp + 0);
      v1.v8  = *(const f16x8*)(vp + 8);
      v2q.v8 = *(const f16x8*)(vp + 16);
      v3.v8  = *(const f16x8*)(vp + 24);
      f16 ps = (f16)p[s];
      f16x2 pp; pp[0] = ps; pp[1] = ps;
#pragma unroll
      for (int k = 0; k < 4; ++k) {
        acc2[k]      += pp * v0.v2[k];
        acc2[4 + k]  += pp * v1.v2[k];
        acc2[8 + k]  += pp * v2q.v2[k];
        acc2[12 + k] += pp * v3.v2[k];
      }
    }
#pragma unroll
    for (int z8 = 0; z8 < 4; ++z8) {
      union VU { f16x8 v8; f16x2 v2[4]; };
      VU ov;
#pragma unroll
      for (int k = 0; k < 4; ++k) ov.v2[k] = acc2[z8 * 4 + k];
      *(f16x8*)(op + z8 * 8) = ov.v8;
    }
  }
}

// ---------------------------------------------------------------------------
// LN2 fused: yln(ROWS,512) f16 = LN(y_h)*g+b
__global__ __launch_bounds__(256) void ln2_fused(const f16* __restrict__ y,
    const float* __restrict__ g, const float* __restrict__ be,
    f16* __restrict__ yln) {
  int wv = threadIdx.x >> 6, lane = threadIdx.x & 63;
  int row = blockIdx.x * 4 + wv;
  const f16x8* yp = (const f16x8*)(y + (size_t)row * 512);
  f16x8 h0 = yp[lane];
  float v[8];
  float s = 0.f, s2 = 0.f;
#pragma unroll
  for (int z = 0; z < 8; ++z) {
    v[z] = (float)h0[z];
    s += v[z]; s2 += v[z] * v[z];
  }
#pragma unroll
  for (int o = 32; o; o >>= 1) { s += __shfl_xor(s, o); s2 += __shfl_xor(s2, o); }
  float m = s * (1.0f / 512.0f);
  float rr = rsqrtf(s2 * (1.0f / 512.0f) - m * m + 1e-5f);
  float4 g0 = ((const float4*)g)[lane * 2], g1 = ((const float4*)g)[lane * 2 + 1];
  float4 b0 = ((const float4*)be)[lane * 2], b1 = ((const float4*)be)[lane * 2 + 1];
  float gg[8] = {g0.x, g0.y, g0.z, g0.w, g1.x, g1.y, g1.z, g1.w};
  float bb[8] = {b0.x, b0.y, b0.z, b0.w, b1.x, b1.y, b1.z, b1.w};
  f16x8 o8;
#pragma unroll
  for (int z = 0; z < 8; ++z)
    o8[z] = (f16)((v[z] - m) * rr * gg[z] + bb[z]);
  *(f16x8*)&yln[(size_t)row * 512 + lane * 8] = o8;
}

// ---------------------------------------------------------------------------
extern "C" void kernel_launch(void* const* d_in, const int* in_sizes, int n_in,
                              void* d_out, int out_size, void* d_ws, size_t ws_size,
                              hipStream_t stream) {
  const float* x      = (const float*)d_in[0];
  const float* qkv_w  = (const float*)d_in[1];
  const float* qkv_b  = (const float*)d_in[2];
  const float* rel    = (const float*)d_in[3];
  const float* proj_w = (const float*)d_in[4];
  const float* proj_b = (const float*)d_in[5];
  const float* w1     = (const float*)d_in[6];
  const float* b1     = (const float*)d_in[7];
  const float* w2     = (const float*)d_in[8];
  const float* b2     = (const float*)d_in[9];
  const float* g1     = (const float*)d_in[10];
  const float* be1    = (const float*)d_in[11];
  const float* g2     = (const float*)d_in[12];
  const float* be2    = (const float*)d_in[13];
  float* out = (float*)d_out;

  // ws layout (bytes): as rounds 6-16.
  char* w8 = (char*)d_ws;
  f16* qkv_wT  = (f16*)(w8 + 1638400);
  f16* proj_wT = qkv_wT + 768 * 256;
  f16* w1T     = proj_wT + 512 * 256;
  f16* w2T     = w1T + 1024 * 512;
  char* P0 = w8 + 4390912;
  f16* qkv_h = (f16*)P0;
  f16* y_h   = (f16*)P0;                      // overlays qkv_h (dead after attn)
  char* P1 = P0 + (size_t)ROWS * 768 * 2;
  f16* xs_h  = (f16*)P1;
  f16* att_h = (f16*)(P1 + (size_t)ROWS * 256 * 2);
  f16* yln   = (f16*)P1;                      // overlays xs/att (dead after proj)
  char* P2 = P1 + (size_t)ROWS * 512 * 2;
  f16* hid = (f16*)P2;

  size_t need_full = 4390912 + (size_t)ROWS * 768 * 2 + (size_t)ROWS * 512 * 2
                   + (size_t)ROWS * 1024 * 2;
  bool full = ws_size >= need_full;

  wtrans_all<<<336, 256, 0, stream>>>(qkv_w, proj_w, w1, w2,
                                      qkv_wT, proj_wT, w1T, w2T);

  ln1_fused<<<ROWS / 64, 256, 0, stream>>>(x, g1, be1, xs_h);

  // 1-D swizzled grids: nrp8 = (M/128)/8
  gemm16<256, 768, 0, 6><<<6 * (ROWS / 128), 256, 0, stream>>>(
      xs_h, qkv_wT, qkv_b, nullptr, qkv_h, nullptr, 0, (ROWS / 128) / 8);

  attn_kernel<<<B_ * 32, 512, 0, stream>>>(qkv_h, rel, att_h);   // 2 windows/block

  gemm16<256, 512, 0, 4><<<4 * (ROWS / 128), 256, 0, stream>>>(
      att_h, proj_wT, proj_b, nullptr, y_h, nullptr, 0, (ROWS / 128) / 8);

  ln2_fused<<<ROWS / 4, 256, 0, stream>>>(y_h, g2, be2, yln);

  if (full) {
    gemm16<512, 1024, 2, 8><<<8 * (ROWS / 128), 256, 0, stream>>>(
        yln, w1T, b1, nullptr, hid, nullptr, 0, (ROWS / 128) / 8);
    gemm16<1024, 512, 3, 4><<<4 * (ROWS / 128), 256, 0, stream>>>(
        hid, w2T, b2, out, nullptr, y_h, 0, (ROWS / 128) / 8);
  } else {
    const int CHUNK = ROWS / 4;  // 25600 rows, 200 panels -> nrp8 = 25
    for (int c = 0; c < 4; ++c) {
      int off = c * CHUNK;
      gemm16<512, 1024, 2, 8><<<8 * (CHUNK / 128), 256, 0, stream>>>(
          yln + (size_t)off * 512, w1T, b1, nullptr, hid, nullptr, off, (CHUNK / 128) / 8);
      gemm16<1024, 512, 3, 4><<<4 * (CHUNK / 128), 256, 0, stream>>>(
          hid, w2T, b2, out, nullptr, y_h, off, (CHUNK / 128) / 8);
    }
  }
  (void)in_sizes; (void)n_in; (void)out_size;
}